// Round 2
// baseline (180.223 us; speedup 1.0000x reference)
//
#include <hip/hip_runtime.h>

// BacklashNet: per-row nonlinear scan (backlash/hysteresis), fully fused,
// software-pipelined across rows.
//
// R1 (70 us kernel): correct single-pass structure but duty-cycle-bound —
// VALUBusy 10.5%, hbm 2.37 TB/s, neither pipe busy. All blocks phase-aligned:
// {load burst | memory-idle compute | store burst}, x2 block generations.
//
// R2: grid 1024 (one generation, 4 blocks/CU exactly), 2 rows per block.
// After staging row i to LDS, immediately issue row i+1's 16 coalesced
// float4 loads into a register prefetch buffer; they stay in flight across
// all of row i's compute (compiler places the vmcnt wait at row i+1's
// ds_writes). Memory and compute now overlap continuously.
//
// Verified machinery kept verbatim from R1 (passed, absmax 7.8e-3):
//   - XOR-swizzled float4 LDS transpose: slot(c,f) = c*16 + (f^(c&15));
//     0 bank conflicts measured.
//   - bit-exact bstep (__f*_rn, reference op order).
//   - acceptance: chunk c+1 valid iff e0[c]==e1[c] bitwise; all-conv =>
//     pass B outputs are exact, no third pass. Rare failure -> uniform
//     cooperative stitch (owner replays from registers).

namespace {

constexpr int kB  = 2048;
constexpr int kT  = 8192;
constexpr int kNC = 128;   // chunks per row == threads per block

__device__ __forceinline__ float bstep(float xv, float prev, float m_lo, float m_up,
                                       float mlc, float muc) {
  float A1 = __fmul_rn(m_lo, xv);
  float B1 = __fadd_rn(A1, mlc);
  float A2 = __fmul_rn(m_up, xv);
  float B2 = __fadd_rn(A2, muc);
  float C  = __fadd_rn(__fadd_rn(B1, A2), muc);
  float u  = __fsub_rn(prev, A2);
  bool  f1 = (B1 <= prev);
  bool  f2 = (u <= muc);
  float hi = f2 ? C  : B1;
  float lo = f2 ? B2 : prev;
  return f1 ? hi : lo;
}

// Stage a register-resident row (coalesced layout) into the swizzled LDS
// transpose buffer. pf[j] holds x4[j*128 + c].
__device__ __forceinline__ void stage_row(float4* __restrict__ sb, int c,
                                          const float4 (&pf)[16]) {
#pragma unroll
  for (int j = 0; j < 16; ++j) {
    const int g = j * 128 + c, cc = g >> 4, f = g & 15;
    sb[cc * 16 + (f ^ (cc & 15))] = pf[j];
  }
}

// Process one fully-staged row: pass A, pass B (+outputs into sb), ballot
// acceptance, rare stitch, coalesced flush. Ends with a barrier so the
// caller may immediately re-stage sb.
__device__ __forceinline__ void process_row(
    float4* __restrict__ sb, float* __restrict__ se0, float* __restrict__ se1,
    int* __restrict__ sflag, float* __restrict__ sfix,
    float* __restrict__ out, int r, int c, float p0r,
    float m_lo, float m_up, float mlc, float muc) {
  // my chunk -> registers (conflict-free b128 column reads)
  float4 xb[16];
#pragma unroll
  for (int f = 0; f < 16; ++f) xb[f] = sb[c * 16 + (f ^ (c & 15))];

  // pass A: exit from guess entry
  float pa = (c == 0) ? p0r : 0.0f;
#pragma unroll
  for (int q = 0; q < 16; ++q) {
    pa = bstep(xb[q].x, pa, m_lo, m_up, mlc, muc);
    pa = bstep(xb[q].y, pa, m_lo, m_up, mlc, muc);
    pa = bstep(xb[q].z, pa, m_lo, m_up, mlc, muc);
    pa = bstep(xb[q].w, pa, m_lo, m_up, mlc, muc);
  }
  se0[c] = pa;
  __syncthreads();

  // pass B: run from e0[c-1], write outputs in-place over x
  float pb = (c == 0) ? p0r : se0[c - 1];
#pragma unroll
  for (int q = 0; q < 16; ++q) {
    float o0 = bstep(xb[q].x, pb, m_lo, m_up, mlc, muc);
    float o1 = bstep(xb[q].y, o0, m_lo, m_up, mlc, muc);
    float o2 = bstep(xb[q].z, o1, m_lo, m_up, mlc, muc);
    float o3 = bstep(xb[q].w, o2, m_lo, m_up, mlc, muc);
    sb[c * 16 + (q ^ (c & 15))] = make_float4(o0, o1, o2, o3);
    pb = o3;
  }
  se1[c] = pb;

  // acceptance: chunk c+1 valid iff e0[c]==e1[c] bitwise
  const bool conv = (c == kNC - 1) || (pa == pb);
  const unsigned long long bal = __ballot(conv);
  if ((c & 63) == 0) sflag[c >> 6] = (bal == ~0ull);
  __syncthreads();  // publishes se1, sb outputs, and flags

  if (!(sflag[0] && sflag[1])) {
    // Rare exact stitch: uniform branches (decisions from LDS-broadcast
    // values), owner replays its chunk from registers.
    float t = se1[0];
    for (int cc = 1; cc < kNC; ++cc) {
      const bool valid = (se0[cc - 1] == t);
      if (valid) {
        t = se1[cc];
      } else {
        __syncthreads();
        if (c == cc) {
          float pf2 = t;
#pragma unroll
          for (int q = 0; q < 16; ++q) {
            float o0 = bstep(xb[q].x, pf2, m_lo, m_up, mlc, muc);
            float o1 = bstep(xb[q].y, o0, m_lo, m_up, mlc, muc);
            float o2 = bstep(xb[q].z, o1, m_lo, m_up, mlc, muc);
            float o3 = bstep(xb[q].w, o2, m_lo, m_up, mlc, muc);
            sb[c * 16 + (q ^ (c & 15))] = make_float4(o0, o1, o2, o3);
            pf2 = o3;
          }
          *sfix = pf2;
        }
        __syncthreads();
        t = *sfix;
      }
    }
    __syncthreads();  // publish rewritten columns
  }

  // coalesced flush: LDS -> out (inverse transpose), 1 KB/instr/wave
  float4* o4 = reinterpret_cast<float4*>(out + (size_t)r * kT);
#pragma unroll
  for (int j = 0; j < 16; ++j) {
    const int g  = j * 128 + c;
    const int cc = g >> 4, f = g & 15;
    o4[g] = sb[cc * 16 + (f ^ (cc & 15))];
  }
  __syncthreads();  // sb reusable by caller
}

__global__ __launch_bounds__(128, 2) void backlash_fused(
    const float* __restrict__ x, const float* __restrict__ p0,
    const float* __restrict__ w, float* __restrict__ out) {
  __shared__ float4 sb[kNC * 16];        // 32 KB swizzled transpose buffer
  __shared__ float  se0[kNC], se1[kNC];  // pass-A / pass-B exits
  __shared__ int    sflag[2];            // per-wave all-converged
  __shared__ float  sfix;                // broadcast slot for stitch fixups

  const int c  = threadIdx.x;
  const int r0 = blockIdx.x * 2;         // two consecutive rows per block
  const float m_lo = w[0], m_up = w[1];
  const float mlc = __fmul_rn(m_lo, w[2]), muc = __fmul_rn(m_up, w[3]);

  const float4* x40 = reinterpret_cast<const float4*>(x + (size_t)r0 * kT);
  const float4* x41 = reinterpret_cast<const float4*>(x + (size_t)(r0 + 1) * kT);

  // row 0: coalesced load -> regs -> swizzled LDS
  float4 pf[16];
#pragma unroll
  for (int j = 0; j < 16; ++j) pf[j] = x40[j * 128 + c];
  stage_row(sb, c, pf);

  // prefetch row 1 into regs — stays in flight during row 0's compute
#pragma unroll
  for (int j = 0; j < 16; ++j) pf[j] = x41[j * 128 + c];

  __syncthreads();
  process_row(sb, se0, se1, sflag, &sfix, out, r0, c, p0[r0],
              m_lo, m_up, mlc, muc);

  // row 1: vmcnt wait lands here, long after issue
  stage_row(sb, c, pf);
  __syncthreads();
  process_row(sb, se0, se1, sflag, &sfix, out, r0 + 1, c, p0[r0 + 1],
              m_lo, m_up, mlc, muc);
}

}  // namespace

extern "C" void kernel_launch(void* const* d_in, const int* in_sizes, int n_in,
                              void* d_out, int out_size, void* d_ws, size_t ws_size,
                              hipStream_t stream) {
  const float* x  = (const float*)d_in[0];   // (B, T, 1) fp32
  const float* p0 = (const float*)d_in[1];   // (B, 1, 1) fp32
  const float* w  = (const float*)d_in[2];   // (4,) fp32
  float* out = (float*)d_out;                // (B, T, 1) fp32
  (void)in_sizes; (void)n_in; (void)out_size; (void)d_ws; (void)ws_size;

  backlash_fused<<<kB / 2, 128, 0, stream>>>(x, p0, w, out);
}

// Round 3
// 123.940 us; speedup vs baseline: 1.4541x; 1.4541x over previous
//
#include <hip/hip_runtime.h>
#include <stdint.h>

// BacklashNet: per-row nonlinear scan (backlash/hysteresis), fully fused,
// double-buffered LDS with async global->LDS staging.
//
// R1 (70 us): single-pass fused, but duty-cycle-bound (VALUBusy 10.5%, HBM
//   2.4 TB/s) — phase-aligned {load|compute|store} bursts, 2 generations.
// R2 (97 us, REGRESSION): register prefetch spilled to scratch (VGPR capped
//   at 128; FETCH/WRITE each +27 MB = pf round-trip). Lesson: don't stage
//   rows in VGPRs.
// R3: stage via __builtin_amdgcn_global_load_lds (16B, async, no VGPR use).
//   LDS dest must be linear (wave-uniform base + lane*16), so the transpose
//   swizzle moves to the SOURCE address (per-lane global addr is free):
//     slot s  <-  x4[ (s>>4)*16 + ((s&15) ^ ((s>>4)&15)) ]
//   (permutation within fully-covered 256B groups -> coalescing unchanged).
//   Double buffer: 2 x 32 KB, 66.6 KB/block -> 2 blocks/CU; grid 512 (one
//   generation), 4 rows/block. Row r+1's loads fly during row r's compute;
//   counted vmcnt waits at row start (16/32/32/16: exact #ops issued after
//   the loads being waited on, FIFO retirement).
//
// Verified machinery kept verbatim (passed, absmax 7.8e-3):
//   - read-side XOR swizzle slot(c,f) = c*16 + (f^(c&15)): 0 bank conflicts
//   - bit-exact bstep (__f*_rn, reference op order)
//   - acceptance: chunk c+1 valid iff e0[c]==e1[c] bitwise; all-converged =>
//     pass B outputs exact; rare failure -> uniform cooperative stitch.

namespace {

constexpr int kB  = 2048;
constexpr int kT  = 8192;
constexpr int kNC = 128;           // chunks per row == threads per block
constexpr int kRPB = 4;            // rows per block
constexpr int kGrid = kB / kRPB;   // 512 blocks = 2/CU, one generation

__device__ __forceinline__ float bstep(float xv, float prev, float m_lo, float m_up,
                                       float mlc, float muc) {
  float A1 = __fmul_rn(m_lo, xv);
  float B1 = __fadd_rn(A1, mlc);
  float A2 = __fmul_rn(m_up, xv);
  float B2 = __fadd_rn(A2, muc);
  float C  = __fadd_rn(__fadd_rn(B1, A2), muc);
  float u  = __fsub_rn(prev, A2);
  bool  f1 = (B1 <= prev);
  bool  f2 = (u <= muc);
  float hi = f2 ? C  : B1;
  float lo = f2 ? B2 : prev;
  return f1 ? hi : lo;
}

// Async-stage one row: 16 x global_load_lds(16B) per thread, linear LDS
// dest (slot s = j*128 + tid), pre-swizzled global source.
__device__ __forceinline__ void issue_row(const float* __restrict__ xrow,
                                          float4* __restrict__ buf, int tid) {
#pragma unroll
  for (int j = 0; j < 16; ++j) {
    const int s  = j * 128 + tid;
    const int cc = s >> 4, fs = s & 15;
    const int g  = cc * 16 + (fs ^ (cc & 15));
    __builtin_amdgcn_global_load_lds(
        (const __attribute__((address_space(1))) uint32_t*)(xrow + 4 * (size_t)g),
        (__attribute__((address_space(3))) uint32_t*)(buf + s),
        16, 0, 0);
  }
}

// Process one fully-staged row out of buf; ends with a barrier so the
// caller may immediately re-stage buf.
__device__ __forceinline__ void process_row(
    float4* __restrict__ sb, float* __restrict__ se0, float* __restrict__ se1,
    int* __restrict__ sflag, float* __restrict__ sfix,
    float* __restrict__ out, int r, int c, float p0r,
    float m_lo, float m_up, float mlc, float muc) {
  // my chunk -> registers (conflict-free swizzled b128 column reads)
  float4 xb[16];
#pragma unroll
  for (int f = 0; f < 16; ++f) xb[f] = sb[c * 16 + (f ^ (c & 15))];

  // pass A: exit from guess entry
  float pa = (c == 0) ? p0r : 0.0f;
#pragma unroll
  for (int q = 0; q < 16; ++q) {
    pa = bstep(xb[q].x, pa, m_lo, m_up, mlc, muc);
    pa = bstep(xb[q].y, pa, m_lo, m_up, mlc, muc);
    pa = bstep(xb[q].z, pa, m_lo, m_up, mlc, muc);
    pa = bstep(xb[q].w, pa, m_lo, m_up, mlc, muc);
  }
  se0[c] = pa;
  __syncthreads();

  // pass B: run from e0[c-1], write outputs in-place over x in LDS
  float pb = (c == 0) ? p0r : se0[c - 1];
#pragma unroll
  for (int q = 0; q < 16; ++q) {
    float o0 = bstep(xb[q].x, pb, m_lo, m_up, mlc, muc);
    float o1 = bstep(xb[q].y, o0, m_lo, m_up, mlc, muc);
    float o2 = bstep(xb[q].z, o1, m_lo, m_up, mlc, muc);
    float o3 = bstep(xb[q].w, o2, m_lo, m_up, mlc, muc);
    sb[c * 16 + (q ^ (c & 15))] = make_float4(o0, o1, o2, o3);
    pb = o3;
  }
  se1[c] = pb;

  // acceptance: chunk c+1 valid iff e0[c]==e1[c] bitwise
  const bool conv = (c == kNC - 1) || (pa == pb);
  const unsigned long long bal = __ballot(conv);
  if ((c & 63) == 0) sflag[c >> 6] = (bal == ~0ull);
  __syncthreads();  // publishes se1, sb outputs, flags

  if (!(sflag[0] && sflag[1])) {
    // Rare exact stitch: uniform branches (decisions from LDS-broadcast
    // values), owner replays its chunk from registers.
    float t = se1[0];
    for (int cc = 1; cc < kNC; ++cc) {
      const bool valid = (se0[cc - 1] == t);
      if (valid) {
        t = se1[cc];
      } else {
        __syncthreads();
        if (c == cc) {
          float pf = t;
#pragma unroll
          for (int q = 0; q < 16; ++q) {
            float o0 = bstep(xb[q].x, pf, m_lo, m_up, mlc, muc);
            float o1 = bstep(xb[q].y, o0, m_lo, m_up, mlc, muc);
            float o2 = bstep(xb[q].z, o1, m_lo, m_up, mlc, muc);
            float o3 = bstep(xb[q].w, o2, m_lo, m_up, mlc, muc);
            sb[c * 16 + (q ^ (c & 15))] = make_float4(o0, o1, o2, o3);
            pf = o3;
          }
          *sfix = pf;
        }
        __syncthreads();
        t = *sfix;
      }
    }
    __syncthreads();  // publish rewritten columns
  }

  // coalesced flush: LDS -> out (inverse transpose), 1 KB/instr/wave
  float4* o4 = reinterpret_cast<float4*>(out + (size_t)r * kT);
#pragma unroll
  for (int j = 0; j < 16; ++j) {
    const int g  = j * 128 + c;
    const int cc = g >> 4, f = g & 15;
    o4[g] = sb[cc * 16 + (f ^ (cc & 15))];
  }
  __syncthreads();  // buf reusable by caller (re-stage is safe)
}

__global__ __launch_bounds__(128, 2) void backlash_fused(
    const float* __restrict__ x, const float* __restrict__ p0,
    const float* __restrict__ w, float* __restrict__ out) {
  __shared__ float4 sb[2][kNC * 16];     // 2 x 32 KB double buffer
  __shared__ float  se0[kNC], se1[kNC];
  __shared__ int    sflag[2];
  __shared__ float  sfix;

  const int c  = threadIdx.x;
  const int r0 = blockIdx.x * kRPB;
  const float m_lo = w[0], m_up = w[1];
  const float mlc = __fmul_rn(m_lo, w[2]), muc = __fmul_rn(m_up, w[3]);

  // prologue: rows 0 and 1 in flight (16 + 16 outstanding per thread)
  issue_row(x + (size_t)r0 * kT,       sb[0], c);
  issue_row(x + (size_t)(r0 + 1) * kT, sb[1], c);

  // row 0 — 16 ops issued after loads(0): vmcnt(16) guarantees loads(0) done
  asm volatile("s_waitcnt vmcnt(16)" ::: "memory");
  __syncthreads();
  process_row(sb[0], se0, se1, sflag, &sfix, out, r0, c, p0[r0],
              m_lo, m_up, mlc, muc);
  issue_row(x + (size_t)(r0 + 2) * kT, sb[0], c);

  // row 1 — after loads(1): stores(0)=16 + loads(2)=16 -> vmcnt(32)
  asm volatile("s_waitcnt vmcnt(32)" ::: "memory");
  __syncthreads();
  process_row(sb[1], se0, se1, sflag, &sfix, out, r0 + 1, c, p0[r0 + 1],
              m_lo, m_up, mlc, muc);
  issue_row(x + (size_t)(r0 + 3) * kT, sb[1], c);

  // row 2 — after loads(2): stores(1)=16 + loads(3)=16 -> vmcnt(32)
  asm volatile("s_waitcnt vmcnt(32)" ::: "memory");
  __syncthreads();
  process_row(sb[0], se0, se1, sflag, &sfix, out, r0 + 2, c, p0[r0 + 2],
              m_lo, m_up, mlc, muc);

  // row 3 — after loads(3): stores(2)=16 -> vmcnt(16)
  asm volatile("s_waitcnt vmcnt(16)" ::: "memory");
  __syncthreads();
  process_row(sb[1], se0, se1, sflag, &sfix, out, r0 + 3, c, p0[r0 + 3],
              m_lo, m_up, mlc, muc);
}

}  // namespace

extern "C" void kernel_launch(void* const* d_in, const int* in_sizes, int n_in,
                              void* d_out, int out_size, void* d_ws, size_t ws_size,
                              hipStream_t stream) {
  const float* x  = (const float*)d_in[0];   // (B, T, 1) fp32
  const float* p0 = (const float*)d_in[1];   // (B, 1, 1) fp32
  const float* w  = (const float*)d_in[2];   // (4,) fp32
  float* out = (float*)d_out;                // (B, T, 1) fp32
  (void)in_sizes; (void)n_in; (void)out_size; (void)d_ws; (void)ws_size;

  backlash_fused<<<kGrid, kNC, 0, stream>>>(x, p0, w, out);
}

// Round 4
// 119.846 us; speedup vs baseline: 1.5038x; 1.0342x over previous
//
#include <hip/hip_runtime.h>
#include <stdint.h>

// BacklashNet: per-row nonlinear scan (backlash/hysteresis), fully fused,
// double-buffered LDS, async global->LDS staging, RAW-BARRIER pipelined.
//
// R1 (70 us): fused single pass; duty-cycle-bound (phase-aligned bursts).
// R2 (97 us, REGRESSION): register prefetch spilled (VGPR capped 128).
// R3 (42 us): global_load_lds double-buffer + counted vmcnt... but every
//   __syncthreads() compiles to s_waitcnt vmcnt(0) lgkmcnt(0) + s_barrier,
//   draining the prefetch at each of the 3-4 barriers/row. The counted
//   waits were dead code; rows still serialized behind full HBM latency.
// R4: raw `s_waitcnt lgkmcnt(0); s_barrier` (inline asm) on the hot path —
//   LDS publish needs lgkm only. Prefetch loads now genuinely span row
//   compute; the ONLY vmcnt waits are the counted row-start ones.
//   Per-wave VMEM FIFO: L0,L1,[S0],L2,[S1],L3,[S2]
//     row0 wait vmcnt(16)  (newer = L1)
//     row1 wait vmcnt(32)  (newer = S0+L2)
//     row2 wait vmcnt(32)  (newer = S1+L3)
//     row3 wait vmcnt(16)  (newer = S2)
//   Rare stitch path keeps __syncthreads (full drain is safe there).
//
// Verified machinery kept byte-identical (passed, absmax 7.8e-3):
//   - source-side XOR swizzle for linear global_load_lds dest;
//     read-side slot(c,f)=c*16+(f^(c&15)): 0 bank conflicts measured
//   - bit-exact bstep (__f*_rn, reference op order)
//   - acceptance: chunk c+1 valid iff e0[c]==e1[c] bitwise; all-converged
//     => pass B outputs exact; failure -> uniform cooperative stitch.

namespace {

constexpr int kB  = 2048;
constexpr int kT  = 8192;
constexpr int kNC = 128;           // chunks per row == threads per block
constexpr int kRPB = 4;            // rows per block
constexpr int kGrid = kB / kRPB;   // 512 blocks = 2/CU, one generation

// Publish LDS writes to the block and rendezvous WITHOUT draining vmcnt
// (prefetch loads stay in flight). Memory clobber fences compiler motion.
#define BAR_LGKM() asm volatile("s_waitcnt lgkmcnt(0)\n\ts_barrier" ::: "memory")

__device__ __forceinline__ float bstep(float xv, float prev, float m_lo, float m_up,
                                       float mlc, float muc) {
  float A1 = __fmul_rn(m_lo, xv);
  float B1 = __fadd_rn(A1, mlc);
  float A2 = __fmul_rn(m_up, xv);
  float B2 = __fadd_rn(A2, muc);
  float C  = __fadd_rn(__fadd_rn(B1, A2), muc);
  float u  = __fsub_rn(prev, A2);
  bool  f1 = (B1 <= prev);
  bool  f2 = (u <= muc);
  float hi = f2 ? C  : B1;
  float lo = f2 ? B2 : prev;
  return f1 ? hi : lo;
}

// Async-stage one row: 16 x global_load_lds(16B) per thread, linear LDS
// dest (slot s = j*128 + tid), pre-swizzled global source.
__device__ __forceinline__ void issue_row(const float* __restrict__ xrow,
                                          float4* __restrict__ buf, int tid) {
#pragma unroll
  for (int j = 0; j < 16; ++j) {
    const int s  = j * 128 + tid;
    const int cc = s >> 4, fs = s & 15;
    const int g  = cc * 16 + (fs ^ (cc & 15));
    __builtin_amdgcn_global_load_lds(
        (const __attribute__((address_space(1))) uint32_t*)(xrow + 4 * (size_t)g),
        (__attribute__((address_space(3))) uint32_t*)(buf + s),
        16, 0, 0);
  }
}

// Process one fully-staged row out of sb. If !kLast, ends with a raw
// lgkm-barrier so the caller may immediately re-stage sb.
template <bool kLast>
__device__ __forceinline__ void process_row(
    float4* __restrict__ sb, float* __restrict__ se0, float* __restrict__ se1,
    int* __restrict__ sflag, float* __restrict__ sfix,
    float* __restrict__ out, int r, int c, float p0r,
    float m_lo, float m_up, float mlc, float muc) {
  // my chunk -> registers (conflict-free swizzled b128 column reads)
  float4 xb[16];
#pragma unroll
  for (int f = 0; f < 16; ++f) xb[f] = sb[c * 16 + (f ^ (c & 15))];

  // pass A: exit from guess entry
  float pa = (c == 0) ? p0r : 0.0f;
#pragma unroll
  for (int q = 0; q < 16; ++q) {
    pa = bstep(xb[q].x, pa, m_lo, m_up, mlc, muc);
    pa = bstep(xb[q].y, pa, m_lo, m_up, mlc, muc);
    pa = bstep(xb[q].z, pa, m_lo, m_up, mlc, muc);
    pa = bstep(xb[q].w, pa, m_lo, m_up, mlc, muc);
  }
  se0[c] = pa;
  BAR_LGKM();  // publish se0; prefetch loads stay in flight

  // pass B: run from e0[c-1], write outputs in-place over x in LDS
  float pb = (c == 0) ? p0r : se0[c - 1];
#pragma unroll
  for (int q = 0; q < 16; ++q) {
    float o0 = bstep(xb[q].x, pb, m_lo, m_up, mlc, muc);
    float o1 = bstep(xb[q].y, o0, m_lo, m_up, mlc, muc);
    float o2 = bstep(xb[q].z, o1, m_lo, m_up, mlc, muc);
    float o3 = bstep(xb[q].w, o2, m_lo, m_up, mlc, muc);
    sb[c * 16 + (q ^ (c & 15))] = make_float4(o0, o1, o2, o3);
    pb = o3;
  }
  se1[c] = pb;

  // acceptance: chunk c+1 valid iff e0[c]==e1[c] bitwise
  const bool conv = (c == kNC - 1) || (pa == pb);
  const unsigned long long bal = __ballot(conv);
  if ((c & 63) == 0) sflag[c >> 6] = (bal == ~0ull);
  BAR_LGKM();  // publish se1, sb outputs, flags

  if (!(sflag[0] && sflag[1])) {
    // Rare exact stitch (uniform branches; decisions from LDS broadcasts).
    // __syncthreads' full drains are correctness-safe here.
    float t = se1[0];
    for (int cc = 1; cc < kNC; ++cc) {
      const bool valid = (se0[cc - 1] == t);
      if (valid) {
        t = se1[cc];
      } else {
        __syncthreads();
        if (c == cc) {
          float pf = t;
#pragma unroll
          for (int q = 0; q < 16; ++q) {
            float o0 = bstep(xb[q].x, pf, m_lo, m_up, mlc, muc);
            float o1 = bstep(xb[q].y, o0, m_lo, m_up, mlc, muc);
            float o2 = bstep(xb[q].z, o1, m_lo, m_up, mlc, muc);
            float o3 = bstep(xb[q].w, o2, m_lo, m_up, mlc, muc);
            sb[c * 16 + (q ^ (c & 15))] = make_float4(o0, o1, o2, o3);
            pf = o3;
          }
          *sfix = pf;
        }
        __syncthreads();
        t = *sfix;
      }
    }
    __syncthreads();  // publish rewritten columns
  }

  // coalesced flush: LDS -> out (inverse transpose), 1 KB/instr/wave
  float4* o4 = reinterpret_cast<float4*>(out + (size_t)r * kT);
#pragma unroll
  for (int j = 0; j < 16; ++j) {
    const int g  = j * 128 + c;
    const int cc = g >> 4, f = g & 15;
    o4[g] = sb[cc * 16 + (f ^ (cc & 15))];
  }
  if (!kLast) {
    // flush ds_reads retired (lgkm) on all waves -> sb safe to re-stage
    BAR_LGKM();
  }
}

__global__ __launch_bounds__(128, 2) void backlash_fused(
    const float* __restrict__ x, const float* __restrict__ p0,
    const float* __restrict__ w, float* __restrict__ out) {
  __shared__ float4 sb[2][kNC * 16];     // 2 x 32 KB double buffer
  __shared__ float  se0[kNC], se1[kNC];
  __shared__ int    sflag[2];
  __shared__ float  sfix;

  const int c  = threadIdx.x;
  const int r0 = blockIdx.x * kRPB;
  const float m_lo = w[0], m_up = w[1];
  const float mlc = __fmul_rn(m_lo, w[2]), muc = __fmul_rn(m_up, w[3]);

  // prologue: rows 0 and 1 in flight (16 + 16 outstanding per thread)
  issue_row(x + (size_t)r0 * kT,       sb[0], c);
  issue_row(x + (size_t)(r0 + 1) * kT, sb[1], c);

  // row 0 — newer-than-L0 = L1(16)
  asm volatile("s_waitcnt vmcnt(16)\n\ts_barrier" ::: "memory");
  process_row<false>(sb[0], se0, se1, sflag, &sfix, out, r0, c, p0[r0],
                     m_lo, m_up, mlc, muc);
  issue_row(x + (size_t)(r0 + 2) * kT, sb[0], c);

  // row 1 — newer-than-L1 = S0(16)+L2(16)
  asm volatile("s_waitcnt vmcnt(32)\n\ts_barrier" ::: "memory");
  process_row<false>(sb[1], se0, se1, sflag, &sfix, out, r0 + 1, c, p0[r0 + 1],
                     m_lo, m_up, mlc, muc);
  issue_row(x + (size_t)(r0 + 3) * kT, sb[1], c);

  // row 2 — newer-than-L2 = S1(16)+L3(16)
  asm volatile("s_waitcnt vmcnt(32)\n\ts_barrier" ::: "memory");
  process_row<false>(sb[0], se0, se1, sflag, &sfix, out, r0 + 2, c, p0[r0 + 2],
                     m_lo, m_up, mlc, muc);

  // row 3 — newer-than-L3 = S2(16)
  asm volatile("s_waitcnt vmcnt(16)\n\ts_barrier" ::: "memory");
  process_row<true>(sb[1], se0, se1, sflag, &sfix, out, r0 + 3, c, p0[r0 + 3],
                    m_lo, m_up, mlc, muc);
}

}  // namespace

extern "C" void kernel_launch(void* const* d_in, const int* in_sizes, int n_in,
                              void* d_out, int out_size, void* d_ws, size_t ws_size,
                              hipStream_t stream) {
  const float* x  = (const float*)d_in[0];   // (B, T, 1) fp32
  const float* p0 = (const float*)d_in[1];   // (B, 1, 1) fp32
  const float* w  = (const float*)d_in[2];   // (4,) fp32
  float* out = (float*)d_out;                // (B, T, 1) fp32
  (void)in_sizes; (void)n_in; (void)out_size; (void)d_ws; (void)ws_size;

  backlash_fused<<<kGrid, kNC, 0, stream>>>(x, p0, w, out);
}